// Round 16
// baseline (550.883 us; speedup 1.0000x reference)
//
#include <hip/hip_runtime.h>
#include <hip/hip_fp16.h>

#define FDIM 128
#define RDIM 20

#define TAB_T 2048              // table cells; TAB_T+1 rows (scalar)
#define TAB_RANGE 12.0f

constexpr int TH = 256;

__device__ __forceinline__ float siluf(float x) { return x / (1.f + __expf(-x)); }

__device__ __forceinline__ void store_h4(__half* p, float a, float b, float c, float d) {
    __half h[4] = {__float2half(a), __float2half(b), __float2half(c), __float2half(d)};
    *(uint2*)p = *(uint2*)h;
}

typedef _Float16 h2v __attribute__((ext_vector_type(2)));
__device__ __forceinline__ float fdot2u(unsigned int a, unsigned int b, float c) {
    union { unsigned int u; h2v h; } ua, ub;
    ua.u = a; ub.u = b;
    return __builtin_amdgcn_fdot2(ua.h, ub.h, c, false);
}

__device__ __forceinline__ float2 h2f2(unsigned int u) {
    return __half22float2(*(const __half2*)&u);
}

// ---------------------------------------------------------------- init: s = emb[z] (v_h zeroed by memset)
__global__ void k_init(const int* __restrict__ z, const float* __restrict__ emb,
                       float* __restrict__ s, __half* __restrict__ s_h, int N) {
    int i = blockIdx.x * blockDim.x + threadIdx.x;
    if (i >= N * FDIM) return;
    int n = i >> 7, f = i & 127;
    float val = emb[z[n] * FDIM + f];
    s[i] = val;
    s_h[i] = __float2half(val);
}

// ---------------------------------------------------------------- weight pack (strided over blockIdx.y)
__global__ void k_packl(const float* __restrict__ src, unsigned int* __restrict__ dst,
                        int C, int total, size_t sstride, size_t dstride) {
    int l = blockIdx.y;
    const float* sp = src + (size_t)l * sstride;
    unsigned int* dp = dst + (size_t)l * dstride;
    int i = blockIdx.x * 256 + threadIdx.x;
    if (i >= total) return;
    int kp = i / C, c = i - kp * C;
    __half2 h = __halves2half2(__float2half(sp[(2*kp) * C + c]),
                               __float2half(sp[(2*kp+1) * C + c]));
    dp[i] = *(unsigned int*)&h;
}

// ---------------------------------------------------------------- CSR build
__global__ void k_hist(const int* __restrict__ erow, int* __restrict__ cursor, int E) {
    int e = blockIdx.x * blockDim.x + threadIdx.x;
    if (e < E) atomicAdd(&cursor[erow[e]], 1);
}

__global__ __launch_bounds__(256) void k_scan1(const int* __restrict__ cursor,
                                               int* __restrict__ rowstart,
                                               int* __restrict__ bsum, int N) {
    __shared__ int sh[256];
    int tid = threadIdx.x;
    int idx = blockIdx.x * 256 + tid;
    int x = (idx < N) ? cursor[idx] : 0;
    sh[tid] = x;
    __syncthreads();
    #pragma unroll
    for (int off = 1; off < 256; off <<= 1) {
        int t = (tid >= off) ? sh[tid - off] : 0;
        __syncthreads();
        sh[tid] += t;
        __syncthreads();
    }
    if (idx < N) rowstart[idx] = sh[tid] - x;
    if (tid == 255) bsum[blockIdx.x] = sh[255];
}

__global__ __launch_bounds__(256) void k_scan2(int* __restrict__ bsum,
                                               int* __restrict__ rowstart, int nb, int N) {
    __shared__ int sh[256];
    __shared__ int carry;
    int tid = threadIdx.x;
    if (tid == 0) carry = 0;
    __syncthreads();
    for (int base = 0; base < nb; base += 256) {
        int idx = base + tid;
        int x = (idx < nb) ? bsum[idx] : 0;
        sh[tid] = x;
        __syncthreads();
        #pragma unroll
        for (int off = 1; off < 256; off <<= 1) {
            int t = (tid >= off) ? sh[tid - off] : 0;
            __syncthreads();
            sh[tid] += t;
            __syncthreads();
        }
        if (idx < nb) bsum[idx] = carry + sh[tid] - x;
        __syncthreads();
        if (tid == 0) carry += sh[255];
        __syncthreads();
    }
    if (tid == 0) rowstart[N] = carry;
}

__global__ __launch_bounds__(256) void k_scan3(int* __restrict__ rowstart,
                                               int* __restrict__ cursor,
                                               const int* __restrict__ bsum, int N) {
    int idx = blockIdx.x * 256 + threadIdx.x;
    if (idx < N) {
        int val = rowstart[idx] + bsum[blockIdx.x];
        rowstart[idx] = val;
        cursor[idx] = val;
    }
}

// ---------------------------------------------------------------- fill + geometry fused:
// place each edge at its CSR slot and write per-slot geometry directly.
__global__ void k_fillgeo(const float* __restrict__ pos, const int* __restrict__ erow,
                          const int* __restrict__ ecol, int* __restrict__ cursor,
                          int2* __restrict__ geo_ci, float4* __restrict__ geo_wd,
                          float inv_step, int E) {
    int e = blockIdx.x * blockDim.x + threadIdx.x;
    if (e >= E) return;
    int rw = erow[e], cl = ecol[e];
    int p = atomicAdd(&cursor[rw], 1);
    float dx = pos[cl*3+0] - pos[rw*3+0];
    float dy = pos[cl*3+1] - pos[rw*3+1];
    float dz = pos[cl*3+2] - pos[rw*3+2];
    float dist = sqrtf(dx*dx + dy*dy + dz*dz + 1e-12f);
    float inv = 1.f / (dist + 1e-8f);
    float u = fminf(dist * inv_step, (float)TAB_T);
    int t0 = min((int)u, TAB_T - 1);
    geo_ci[p] = make_int2(cl, t0);
    geo_wd[p] = make_float4(u - (float)t0, dx*inv, dy*inv, dz*inv);
}

// ---------------------------------------------------------------- filter-MLP table build (all layers, fp16 out)
__global__ __launch_bounds__(TH) void k_table(
    const float* __restrict__ centers, const float* __restrict__ gamma,
    const float* __restrict__ fw1b, const float* __restrict__ fb1b,
    const float* __restrict__ fw2b, const float* __restrict__ fb2b,
    __half* __restrict__ tabb, float step)
{
    __shared__ float sh_rbf[32][RDIM];
    __shared__ float sh_ht[FDIM][33];
    __shared__ float sh_w[32][3 * FDIM + 4];

    const int l   = blockIdx.y;
    const float* fw1 = fw1b + (size_t)l * RDIM * FDIM;
    const float* fb1 = fb1b + (size_t)l * FDIM;
    const float* fw2 = fw2b + (size_t)l * FDIM * 3 * FDIM;
    const float* fb2 = fb2b + (size_t)l * 3 * FDIM;
    __half* tab = tabb + (size_t)l * (TAB_T + 1) * 384;

    const int p0  = blockIdx.x * 32;
    const int tid = threadIdx.x;

    for (int i = tid; i < 32 * RDIM; i += TH) {
        int p = i / RDIM, r = i - p * RDIM;
        float d = (float)(p0 + p) * step - centers[r];
        sh_rbf[p][r] = __expf(-gamma[r] * d * d);
    }
    __syncthreads();
    for (int i = tid; i < 32 * FDIM; i += TH) {
        int p = i >> 7, f = i & 127;
        float acc = fb1[f];
        #pragma unroll
        for (int r = 0; r < RDIM; ++r) acc += sh_rbf[p][r] * fw1[r * FDIM + f];
        sh_ht[f][p] = siluf(acc);
    }

    const int eq = tid & 7;
    const int fq = tid >> 3;
    const int f0 = fq * 4;

    float pg[3][4][4];
    #pragma unroll
    for (int g3 = 0; g3 < 3; ++g3)
        #pragma unroll
        for (int ee = 0; ee < 4; ++ee)
            #pragma unroll
            for (int i = 0; i < 4; ++i) pg[g3][ee][i] = fb2[g3 * FDIM + f0 + i];

    const int kkr = tid >> 3;
    const int t8  = tid & 7;
    for (int kc = 0; kc < 4; ++kc) {
        __syncthreads();
        #pragma unroll
        for (int j = 0; j < 12; ++j) {
            int g = (t8 * 12 + j) * 4;
            float4 w4 = *(const float4*)&fw2[(size_t)(kc * 32 + kkr) * (3 * FDIM) + g];
            *(float4*)&sh_w[kkr][g] = w4;
        }
        __syncthreads();
        #pragma unroll 4
        for (int kk = 0; kk < 32; ++kk) {
            float hv[4];
            #pragma unroll
            for (int ee = 0; ee < 4; ++ee) hv[ee] = sh_ht[kc * 32 + kk][4 * eq + ee];
            #pragma unroll
            for (int g3 = 0; g3 < 3; ++g3) {
                float4 w4 = *(const float4*)&sh_w[kk][g3 * FDIM + f0];
                #pragma unroll
                for (int ee = 0; ee < 4; ++ee) {
                    pg[g3][ee][0] += hv[ee] * w4.x;
                    pg[g3][ee][1] += hv[ee] * w4.y;
                    pg[g3][ee][2] += hv[ee] * w4.z;
                    pg[g3][ee][3] += hv[ee] * w4.w;
                }
            }
        }
    }

    #pragma unroll
    for (int ee = 0; ee < 4; ++ee) {
        int pt = p0 + 4 * eq + ee;
        if (pt <= TAB_T) {
            #pragma unroll
            for (int g3 = 0; g3 < 3; ++g3)
                store_h4(&tab[(size_t)pt * 384 + g3 * FDIM + f0],
                         pg[g3][ee][0], pg[g3][ee][1], pg[g3][ee][2], pg[g3][ee][3]);
        }
    }
}

// ---------------------------------------------------------------- repack: tab4[t][f] = uint4{ss-pair, vv-pair, sv-pair, 0}
__global__ __launch_bounds__(256) void k_repack4(const __half* __restrict__ tab,
                                                 uint4* __restrict__ tab4) {
    int l = blockIdx.y;
    const __half* t = tab + (size_t)l * (TAB_T + 1) * 384;
    uint4* t4 = tab4 + (size_t)l * TAB_T * 128;
    int i = blockIdx.x * 256 + threadIdx.x;        // < TAB_T*128
    int tt = i >> 7, f = i & 127;
    const __half* tp = t + (size_t)tt * 384;
    __half2 ss = __halves2half2(tp[f],       tp[384 + f]);
    __half2 vv = __halves2half2(tp[128 + f], tp[512 + f]);
    __half2 sv = __halves2half2(tp[256 + f], tp[640 + f]);
    uint4 o;
    o.x = *(unsigned int*)&ss;
    o.y = *(unsigned int*)&vv;
    o.z = *(unsigned int*)&sv;
    o.w = 0u;
    t4[i] = o;
}

// ---------------------------------------------------------------- gather message kernel (fp16, uint4 table)
__global__ __launch_bounds__(128) void k_gather(
    const int* __restrict__ rowstart,
    const int2* __restrict__ geo_ci, const float4* __restrict__ geo_wd,
    const uint4* __restrict__ tab4, const __half* __restrict__ s_h,
    const __half* __restrict__ v_h,
    __half* __restrict__ m_s_h, __half* __restrict__ vnorm_h, __half* __restrict__ m_v_h,
    int withv, int N)
{
    __shared__ int   sh_col[32];
    __shared__ int   sh_t0[32];
    __shared__ float sh_w[32];
    __shared__ float sh_d0[32], sh_d1[32], sh_d2[32];

    const int n   = blockIdx.x;
    const int tid = threadIdx.x;
    const int lo  = rowstart[n], hi = rowstart[n + 1];

    float acc_s = 0.f, av0 = 0.f, av1 = 0.f, av2 = 0.f;

    for (int base = lo; base < hi; base += 32) {
        const int ne = min(32, hi - base);
        __syncthreads();
        if (tid < 32) {
            int idx = base + tid;
            if (tid < ne) {
                int2   ci = geo_ci[idx];
                float4 wd = geo_wd[idx];
                sh_col[tid] = ci.x; sh_t0[tid] = ci.y;
                sh_w[tid] = wd.x;
                sh_d0[tid] = wd.y; sh_d1[tid] = wd.z; sh_d2[tid] = wd.w;
            } else {
                sh_col[tid] = 0; sh_t0[tid] = 0; sh_w[tid] = 0.f;
                sh_d0[tid] = sh_d1[tid] = sh_d2[tid] = 0.f;
            }
        }
        __syncthreads();
        if (withv) {
            #pragma unroll 2
            for (int el = 0; el < ne; ++el) {
                int   cl = sh_col[el];
                int   t0 = sh_t0[el];
                float w  = sh_w[el];
                uint4 tv = tab4[(size_t)t0 * 128 + tid];
                float2 pss2 = h2f2(tv.x);
                float2 pvv2 = h2f2(tv.y);
                float2 psv2 = h2f2(tv.z);
                float pss = pss2.x + w * (pss2.y - pss2.x);
                float pvv = pvv2.x + w * (pvv2.y - pvv2.x);
                float psv = psv2.x + w * (psv2.y - psv2.x);
                float sc = __half2float(s_h[(size_t)cl * FDIM + tid]);
                const __half* vp = v_h + (size_t)cl * 3 * FDIM + tid;
                float svs = psv * sc;
                acc_s += pss * sc;
                av0 += pvv * __half2float(vp[0])        + svs * sh_d0[el];
                av1 += pvv * __half2float(vp[FDIM])     + svs * sh_d1[el];
                av2 += pvv * __half2float(vp[2*FDIM])   + svs * sh_d2[el];
            }
        } else {
            #pragma unroll 2
            for (int el = 0; el < ne; ++el) {
                int   cl = sh_col[el];
                int   t0 = sh_t0[el];
                float w  = sh_w[el];
                uint4 tv = tab4[(size_t)t0 * 128 + tid];
                float2 pss2 = h2f2(tv.x);
                float2 psv2 = h2f2(tv.z);
                float pss = pss2.x + w * (pss2.y - pss2.x);
                float psv = psv2.x + w * (psv2.y - psv2.x);
                float sc = __half2float(s_h[(size_t)cl * FDIM + tid]);
                float svs = psv * sc;
                acc_s += pss * sc;
                av0 += svs * sh_d0[el];
                av1 += svs * sh_d1[el];
                av2 += svs * sh_d2[el];
            }
        }
    }

    m_s_h[(size_t)n * FDIM + tid]  = __float2half(acc_s);
    vnorm_h[(size_t)n * FDIM + tid] = __float2half(sqrtf(av0*av0 + av1*av1 + av2*av2 + 1e-12f));
    __half* mh = m_v_h + (size_t)n * 3 * FDIM + tid;
    mh[0]      = __float2half(av0);
    mh[FDIM]   = __float2half(av1);
    mh[2*FDIM] = __float2half(av2);
}

// ---------------------------------------------------------------- GEMM 1: u1 = silu(X @ uw1 + ub1), fdot2
__global__ __launch_bounds__(128) void k_mlp1(
    const __half* __restrict__ s_h, const __half* __restrict__ m_s_h,
    const __half* __restrict__ vnorm_h,
    const unsigned int* __restrict__ uw1p,   // [192][128] half2-pairs
    const float* __restrict__ ub1,
    __half* __restrict__ u1_h, int N)
{
    __shared__ unsigned int shA2[8][36];   // [kpair][row]
    __shared__ unsigned int shB2[8][68];   // [kpair][col(64)]

    const int tid = threadIdx.x;           // 0..127
    const int n0  = blockIdx.x * 32;
    const int cb  = blockIdx.y * 64;
    const int tx  = tid & 15, ty = tid >> 4;   // ty 0..7
    const int cA  = tx * 4;
    const int r0  = ty * 4;
    const int rs  = tid >> 2;              // A staging row 0..31
    const int kp0 = (tid & 3) * 2;         // A staging kpair base

    float acc[4][4];
    {
        float4 b4 = *(const float4*)&ub1[cb + cA];
        #pragma unroll
        for (int i = 0; i < 4; ++i) {
            acc[i][0] = b4.x; acc[i][1] = b4.y; acc[i][2] = b4.z; acc[i][3] = b4.w;
        }
    }

    uint2 pa; uint4 pb;

#define MLP1_LOAD(kc) do { \
        pa = make_uint2(0u, 0u); \
        { int kg = (kc) * 16 + (tid & 3) * 4; int n = n0 + rs; \
          if (n < N) { \
              const __half* base; \
              if (kg < 128)      base = &s_h[(size_t)n * FDIM + kg]; \
              else if (kg < 256) base = &m_s_h[(size_t)n * FDIM + kg - 128]; \
              else               base = &vnorm_h[(size_t)n * FDIM + kg - 256]; \
              pa = *(const uint2*)base; } } \
        pb = *(const uint4*)&uw1p[(size_t)((kc)*8 + ty) * FDIM + cb + 4*tx]; \
    } while (0)

    MLP1_LOAD(0);
    for (int kc = 0; kc < 24; ++kc) {
        __syncthreads();
        shA2[kp0][rs]     = pa.x;
        shA2[kp0 + 1][rs] = pa.y;
        *(uint4*)&shB2[ty][4*tx] = pb;
        if (kc + 1 < 24) MLP1_LOAD(kc + 1);
        __syncthreads();
        #pragma unroll
        for (int kp = 0; kp < 8; ++kp) {
            unsigned int b0 = shB2[kp][cA+0], b1 = shB2[kp][cA+1];
            unsigned int b2 = shB2[kp][cA+2], b3 = shB2[kp][cA+3];
            #pragma unroll
            for (int i = 0; i < 4; ++i) {
                unsigned int ai = shA2[kp][r0 + i];
                acc[i][0] = fdot2u(ai, b0, acc[i][0]);
                acc[i][1] = fdot2u(ai, b1, acc[i][1]);
                acc[i][2] = fdot2u(ai, b2, acc[i][2]);
                acc[i][3] = fdot2u(ai, b3, acc[i][3]);
            }
        }
    }
#undef MLP1_LOAD

    #pragma unroll
    for (int i = 0; i < 4; ++i) {
        int n = n0 + r0 + i;
        if (n < N) {
            store_h4(&u1_h[(size_t)n * FDIM + cb + cA],
                     siluf(acc[i][0]), siluf(acc[i][1]), siluf(acc[i][2]), siluf(acc[i][3]));
        }
    }
}

// ---------------------------------------------------------------- GEMM 2: upd = u1 @ uw2 + ub2, fused apply, fdot2
__global__ __launch_bounds__(128) void k_mlp2(
    const __half* __restrict__ u1_h,
    const unsigned int* __restrict__ uw2p,   // [64][384] half2-pairs
    const float* __restrict__ ub2,
    float* __restrict__ s, __half* __restrict__ v_h, const __half* __restrict__ m_v_h,
    __half* __restrict__ s_h, int N)
{
    __shared__ unsigned int shU2[64][33];   // [kpair][row]
    __shared__ unsigned int shB2[8][68];

    const int tid = threadIdx.x;           // 0..127
    const int n0  = blockIdx.x * 32;
    const int cb  = blockIdx.y * 64;
    const int tx  = tid & 15, ty = tid >> 4;
    const int cA  = tx * 4;
    const int r0  = ty * 4;

    // stage u1 tile (32 rows x 64 kpairs) once
    #pragma unroll
    for (int it = 0; it < 4; ++it) {
        int idx = it * 128 + tid;
        int row = idx >> 4;          // 0..31
        int c8  = (idx & 15) * 8;
        int n = n0 + row;
        uint4 u = make_uint4(0u,0u,0u,0u);
        if (n < N) u = *(const uint4*)&u1_h[(size_t)n * FDIM + c8];
        int kpb = c8 >> 1;
        shU2[kpb + 0][row] = u.x;
        shU2[kpb + 1][row] = u.y;
        shU2[kpb + 2][row] = u.z;
        shU2[kpb + 3][row] = u.w;
    }

    uint4 pb;
#define MLP2_LOADB(g, kc) do { \
        pb = *(const uint4*)&uw2p[(size_t)((kc)*8 + ty) * (3*FDIM) + (g) * FDIM + cb + 4*tx]; \
    } while (0)

    MLP2_LOADB(0, 0);
    float alpha[4][4];

    for (int g = 0; g < 3; ++g) {
        float acc2[4][4];
        {
            float4 b4 = *(const float4*)&ub2[g * FDIM + cb + cA];
            #pragma unroll
            for (int i = 0; i < 4; ++i) {
                acc2[i][0]=b4.x; acc2[i][1]=b4.y; acc2[i][2]=b4.z; acc2[i][3]=b4.w;
            }
        }
        for (int kc = 0; kc < 8; ++kc) {
            __syncthreads();
            *(uint4*)&shB2[ty][4*tx] = pb;
            if (kc + 1 < 8)      MLP2_LOADB(g, kc + 1);
            else if (g + 1 < 3)  MLP2_LOADB(g + 1, 0);
            __syncthreads();
            #pragma unroll
            for (int kp = 0; kp < 8; ++kp) {
                int kpg = kc * 8 + kp;
                unsigned int b0 = shB2[kp][cA+0], b1 = shB2[kp][cA+1];
                unsigned int b2 = shB2[kp][cA+2], b3 = shB2[kp][cA+3];
                #pragma unroll
                for (int i = 0; i < 4; ++i) {
                    unsigned int uv = shU2[kpg][r0 + i];
                    acc2[i][0] = fdot2u(uv, b0, acc2[i][0]);
                    acc2[i][1] = fdot2u(uv, b1, acc2[i][1]);
                    acc2[i][2] = fdot2u(uv, b2, acc2[i][2]);
                    acc2[i][3] = fdot2u(uv, b3, acc2[i][3]);
                }
            }
        }

        if (g == 0) {
            #pragma unroll
            for (int i = 0; i < 4; ++i) {
                int n = n0 + r0 + i;
                if (n < N) {
                    float4 s0 = *(const float4*)&s[(size_t)n * FDIM + cb + cA];
                    s0.x += acc2[i][0]; s0.y += acc2[i][1]; s0.z += acc2[i][2]; s0.w += acc2[i][3];
                    *(float4*)&s[(size_t)n * FDIM + cb + cA] = s0;
                    store_h4(&s_h[(size_t)n * FDIM + cb + cA], s0.x, s0.y, s0.z, s0.w);
                }
            }
        } else if (g == 1) {
            #pragma unroll
            for (int i = 0; i < 4; ++i)
                #pragma unroll
                for (int j = 0; j < 4; ++j) alpha[i][j] = acc2[i][j];
        } else {
            #pragma unroll
            for (int i = 0; i < 4; ++i) {
                int n = n0 + r0 + i;
                if (n < N) {
                    #pragma unroll
                    for (int k = 0; k < 3; ++k) {
                        __half* vhp = v_h + ((size_t)n * 3 + k) * FDIM + cb + cA;
                        const __half* mp = m_v_h + ((size_t)n * 3 + k) * FDIM + cb + cA;
                        __half vh[4], mh[4];
                        *(uint2*)vh = *(const uint2*)vhp;
                        *(uint2*)mh = *(const uint2*)mp;
                        float nv[4];
                        #pragma unroll
                        for (int j = 0; j < 4; ++j)
                            nv[j] = alpha[i][j] * __half2float(vh[j])
                                  + acc2[i][j] * __half2float(mh[j]);
                        store_h4(vhp, nv[0], nv[1], nv[2], nv[3]);
                    }
                }
            }
        }
    }
#undef MLP2_LOADB
}

// ---------------------------------------------------------------- energy head GEMM, fdot2 (grid = NB x S)
__global__ __launch_bounds__(256) void k_energy3(
    const unsigned int* __restrict__ ew1p,   // [S][64][128] half2-pairs
    const float* __restrict__ eb1,
    const float* __restrict__ ew2, const float* __restrict__ eb2,
    const __half* __restrict__ s_h, const int* __restrict__ batch,
    float* __restrict__ energies, int N, int S)
{
    __shared__ unsigned int shA2[64][66];   // [kpair][row]
    __shared__ unsigned int shB2[8][132];

    const int tid = threadIdx.x;
    const int n0  = blockIdx.x * 64;
    const int st  = blockIdx.y;
    const int tx  = tid & 15, ty = tid >> 4;
    const int cA  = tx * 4, cB = 64 + tx * 4;
    const int r0  = ty * 4;

    #pragma unroll
    for (int it = 0; it < 4; ++it) {
        int idx = it * 256 + tid;
        int row = idx >> 4;
        int c8  = (idx & 15) * 8;
        int n = n0 + row;
        uint4 u = make_uint4(0u,0u,0u,0u);
        if (n < N) u = *(const uint4*)&s_h[(size_t)n * FDIM + c8];
        int kpb = c8 >> 1;
        shA2[kpb + 0][row] = u.x;
        shA2[kpb + 1][row] = u.y;
        shA2[kpb + 2][row] = u.z;
        shA2[kpb + 3][row] = u.w;
    }

    uint2 pb, pb2;
#define EN_LOADB(kc) do { \
        pb = *(const uint2*)&ew1p[(size_t)st * 64 * FDIM + (size_t)((kc)*8 + (tid >> 6)) * FDIM + 2*(tid & 63)]; \
        pb2 = *(const uint2*)&ew1p[(size_t)st * 64 * FDIM + (size_t)((kc)*8 + 4 + (tid >> 6)) * FDIM + 2*(tid & 63)]; \
    } while (0)

    EN_LOADB(0);
    float acc[4][8];
    {
        float4 bA = *(const float4*)&eb1[st * FDIM + cA];
        float4 bB = *(const float4*)&eb1[st * FDIM + cB];
        #pragma unroll
        for (int i = 0; i < 4; ++i) {
            acc[i][0]=bA.x; acc[i][1]=bA.y; acc[i][2]=bA.z; acc[i][3]=bA.w;
            acc[i][4]=bB.x; acc[i][5]=bB.y; acc[i][6]=bB.z; acc[i][7]=bB.w;
        }
    }

    for (int kc = 0; kc < 8; ++kc) {
        __syncthreads();
        {
            int kp = tid >> 6;            // 0..3
            int c2 = 2 * (tid & 63);
            shB2[kp][c2]     = pb.x;  shB2[kp][c2 + 1]     = pb.y;
            shB2[kp + 4][c2] = pb2.x; shB2[kp + 4][c2 + 1] = pb2.y;
        }
        if (kc + 1 < 8) EN_LOADB(kc + 1);
        __syncthreads();
        #pragma unroll
        for (int kp = 0; kp < 8; ++kp) {
            int kpg = kc * 8 + kp;
            unsigned int b0 = shB2[kp][cA+0], b1 = shB2[kp][cA+1];
            unsigned int b2 = shB2[kp][cA+2], b3 = shB2[kp][cA+3];
            unsigned int b4 = shB2[kp][cB+0], b5 = shB2[kp][cB+1];
            unsigned int b6 = shB2[kp][cB+2], b7 = shB2[kp][cB+3];
            #pragma unroll
            for (int i = 0; i < 4; ++i) {
                unsigned int ai = shA2[kpg][r0 + i];
                acc[i][0] = fdot2u(ai, b0, acc[i][0]);
                acc[i][1] = fdot2u(ai, b1, acc[i][1]);
                acc[i][2] = fdot2u(ai, b2, acc[i][2]);
                acc[i][3] = fdot2u(ai, b3, acc[i][3]);
                acc[i][4] = fdot2u(ai, b4, acc[i][4]);
                acc[i][5] = fdot2u(ai, b5, acc[i][5]);
                acc[i][6] = fdot2u(ai, b6, acc[i][6]);
                acc[i][7] = fdot2u(ai, b7, acc[i][7]);
            }
        }
    }
#undef EN_LOADB

    float4 wA = *(const float4*)&ew2[st * FDIM + cA];
    float4 wB = *(const float4*)&ew2[st * FDIM + cB];
    float p[4];
    #pragma unroll
    for (int i = 0; i < 4; ++i) {
        p[i]  = siluf(acc[i][0])*wA.x + siluf(acc[i][1])*wA.y
              + siluf(acc[i][2])*wA.z + siluf(acc[i][3])*wA.w;
        p[i] += siluf(acc[i][4])*wB.x + siluf(acc[i][5])*wB.y
              + siluf(acc[i][6])*wB.z + siluf(acc[i][7])*wB.w;
    }
    #pragma unroll
    for (int m = 1; m <= 8; m <<= 1) {
        #pragma unroll
        for (int i = 0; i < 4; ++i) p[i] += __shfl_xor(p[i], m, 64);
    }
    if (tx == 0) {
        float b2 = eb2[st];
        #pragma unroll
        for (int i = 0; i < 4; ++i) {
            int n = n0 + r0 + i;
            if (n < N) atomicAdd(&energies[batch[n] * S + st], p[i] + b2);
        }
    }
}

// ---------------------------------------------------------------- dipole / nac heads (v_h fp16, half2 lanes)
__global__ void k_vec(const __half* __restrict__ v_h, const float* __restrict__ dipole_w,
                      const float* __restrict__ nac_w, const int* __restrict__ batch,
                      float* __restrict__ dipoles, float* __restrict__ nac, int N)
{
    int n = blockIdx.x * 4 + (threadIdx.x >> 6);
    int lane = threadIdx.x & 63;
    if (n >= N) return;
    int f2 = lane * 2;
    const __half* vb = v_h + (size_t)n * 3 * FDIM;
    float2 v0 = __half22float2(*(const __half2*)&vb[f2]);
    float2 v1 = __half22float2(*(const __half2*)&vb[FDIM + f2]);
    float2 v2 = __half22float2(*(const __half2*)&vb[2*FDIM + f2]);
    float2 wd = *(const float2*)&dipole_w[f2];
    float pd[3];
    pd[0] = wd.x * v0.x + wd.y * v0.y;
    pd[1] = wd.x * v1.x + wd.y * v1.y;
    pd[2] = wd.x * v2.x + wd.y * v2.y;
    float pn[3][3];
    #pragma unroll
    for (int p = 0; p < 3; ++p) {
        float2 wn = *(const float2*)&nac_w[p * FDIM + f2];
        pn[p][0] = wn.x * v0.x + wn.y * v0.y;
        pn[p][1] = wn.x * v1.x + wn.y * v1.y;
        pn[p][2] = wn.x * v2.x + wn.y * v2.y;
    }
    #pragma unroll
    for (int d = 32; d > 0; d >>= 1) {
        #pragma unroll
        for (int k = 0; k < 3; ++k) pd[k] += __shfl_down(pd[k], d, 64);
        #pragma unroll
        for (int p = 0; p < 3; ++p)
            #pragma unroll
            for (int k = 0; k < 3; ++k) pn[p][k] += __shfl_down(pn[p][k], d, 64);
    }
    if (lane == 0) {
        int m = batch[n];
        #pragma unroll
        for (int k = 0; k < 3; ++k) atomicAdd(&dipoles[m * 3 + k], pd[k]);
        #pragma unroll
        for (int p = 0; p < 3; ++p)
            #pragma unroll
            for (int k = 0; k < 3; ++k) atomicAdd(&nac[(m * 3 + p) * 3 + k], pn[p][k]);
    }
}

// ---------------------------------------------------------------- per-molecule heads
__global__ __launch_bounds__(128) void k_heads(
    const float* __restrict__ aw1, const float* __restrict__ ab1,
    const float* __restrict__ aw2, const float* __restrict__ ab2,
    const float* __restrict__ yw1, const float* __restrict__ yb1,
    const float* __restrict__ yw2, const float* __restrict__ yb2,
    const float* __restrict__ energies, const float* __restrict__ nac,
    float* __restrict__ lam, float* __restrict__ phi_y, int M, int S)
{
    __shared__ float sh_in[8];
    __shared__ float sh_red[2];
    int m = blockIdx.x;
    if (m >= M) return;
    int tid = threadIdx.x;
    if (tid == 0) {
        float e0 = energies[m * S];
        for (int j = 0; j < 3; ++j) sh_in[j] = energies[m * S + 1 + j] - e0;
        for (int p = 0; p < 3; ++p) {
            float a = nac[(m * 3 + p) * 3 + 0];
            float b = nac[(m * 3 + p) * 3 + 1];
            float c = nac[(m * 3 + p) * 3 + 2];
            sh_in[3 + p] = sqrtf(a*a + b*b + c*c + 1e-12f);
        }
    }
    __syncthreads();
    float pa = 0.f;
    if (tid < 64) {
        float h = ab1[tid];
        #pragma unroll
        for (int j = 0; j < 3; ++j) h += sh_in[j] * aw1[j * 64 + tid];
        pa = siluf(h) * aw2[tid];
    }
    float h2 = yb1[tid];
    #pragma unroll
    for (int j = 0; j < 6; ++j) h2 += sh_in[j] * yw1[j * 128 + tid];
    float py = siluf(h2) * yw2[tid];
    #pragma unroll
    for (int d = 32; d > 0; d >>= 1) {
        pa += __shfl_down(pa, d, 64);
        py += __shfl_down(py, d, 64);
    }
    int wid = tid >> 6, lane = tid & 63;
    if (lane == 0) sh_red[wid] = py;
    __syncthreads();
    if (tid == 0) {
        lam[m] = pa + ab2[0];
        float yt = sh_red[0] + sh_red[1] + yb2[0];
        phi_y[m] = 1.f / (1.f + __expf(-yt));
    }
}

// ---------------------------------------------------------------- launch
extern "C" void kernel_launch(void* const* d_in, const int* in_sizes, int n_in,
                              void* d_out, int out_size, void* d_ws, size_t ws_size,
                              hipStream_t stream)
{
    const int*   z        = (const int*)  d_in[0];
    const float* pos      = (const float*)d_in[1];
    const int*   eidx     = (const int*)  d_in[2];
    const int*   batch    = (const int*)  d_in[3];
    const float* emb      = (const float*)d_in[5];
    const float* centers  = (const float*)d_in[6];
    const float* gamma    = (const float*)d_in[7];
    const float* fw1      = (const float*)d_in[8];
    const float* fb1      = (const float*)d_in[9];
    const float* fw2      = (const float*)d_in[10];
    const float* fb2      = (const float*)d_in[11];
    const float* uw1      = (const float*)d_in[12];
    const float* ub1      = (const float*)d_in[13];
    const float* uw2      = (const float*)d_in[14];
    const float* ub2      = (const float*)d_in[15];
    const float* ew1      = (const float*)d_in[16];
    const float* eb1      = (const float*)d_in[17];
    const float* ew2      = (const float*)d_in[18];
    const float* eb2      = (const float*)d_in[19];
    const float* dipole_w = (const float*)d_in[20];
    const float* nac_w    = (const float*)d_in[21];
    const float* aw1      = (const float*)d_in[22];
    const float* ab1      = (const float*)d_in[23];
    const float* aw2      = (const float*)d_in[24];
    const float* ab2      = (const float*)d_in[25];
    const float* yw1      = (const float*)d_in[26];
    const float* yb1      = (const float*)d_in[27];
    const float* yw2      = (const float*)d_in[28];
    const float* yb2      = (const float*)d_in[29];

    const int N = in_sizes[0];
    const int E = in_sizes[2] / 2;
    const int S = in_sizes[19];
    const int P = in_sizes[21] / FDIM;
    const int L = in_sizes[9] / FDIM;
    const int M = out_size / (S + 3 + P * 3 + 2);

    const size_t NF = (size_t)N * FDIM;
    float*   s       = (float*)d_ws;                   // NF fp32
    __half*  s_h     = (__half*)(s + NF);              // NF
    __half*  v_h     = s_h + NF;                       // 3 NF (authoritative v)
    __half*  m_s_h   = v_h + 3 * NF;                   // NF
    __half*  vnorm_h = m_s_h + NF;                     // NF
    __half*  m_v_h   = vnorm_h + NF;                   // 3 NF
    __half*  u1_hb   = m_v_h + 3 * NF;                 // NF
    unsigned int* uw1p = (unsigned int*)(u1_hb + NF);  // L * 192*128
    unsigned int* uw2p = uw1p + (size_t)L * 192 * 128; // L * 64*384
    unsigned int* ew1p = uw2p + (size_t)L * 64 * 384;  // S * 64*128
    __half*  tab     = (__half*)(ew1p + (size_t)S * 64 * 128);   // L * (TAB_T+1)*384
    uint4*   tab4    = (uint4*)(tab + (size_t)L * (TAB_T + 1) * 384);  // L * TAB_T * 128 uint4
    float4*  geo_wd  = (float4*)(tab4 + (size_t)L * TAB_T * 128);      // E
    int2*    geo_ci  = (int2*)(geo_wd + E);                            // E
    int* rowstart = (int*)(geo_ci + E);
    int* cursor   = rowstart + (N + 1);
    int* bsum     = cursor + N;

    float* out      = (float*)d_out;
    float* energies = out;
    float* dipoles  = energies + (size_t)M * S;
    float* nac      = dipoles  + (size_t)M * 3;
    float* lam      = nac      + (size_t)M * P * 3;
    float* phi_y    = lam      + M;

    const int* erow = eidx;
    const int* ecol = eidx + E;

    const float step = TAB_RANGE / (float)TAB_T;
    const float inv_step = (float)TAB_T / TAB_RANGE;
    const int NB  = (N + 63) / 64;
    const int NB2 = (N + 31) / 32;
    const int NSB = (N + 255) / 256;

    hipMemsetAsync(d_out, 0, (size_t)out_size * sizeof(float), stream);
    hipMemsetAsync(cursor, 0, (size_t)N * sizeof(int), stream);
    hipMemsetAsync(v_h, 0, 3 * NF * sizeof(__half), stream);   // fp16 zero == 0x0000
    k_hist<<<(E + 255) / 256, 256, 0, stream>>>(erow, cursor, E);
    k_scan1<<<NSB, 256, 0, stream>>>(cursor, rowstart, bsum, N);
    k_scan2<<<1, 256, 0, stream>>>(bsum, rowstart, NSB, N);
    k_scan3<<<NSB, 256, 0, stream>>>(rowstart, cursor, bsum, N);
    k_fillgeo<<<(E + 255) / 256, 256, 0, stream>>>(pos, erow, ecol, cursor,
                                                   geo_ci, geo_wd, inv_step, E);
    k_init<<<(N * FDIM + 255) / 256, 256, 0, stream>>>(z, emb, s, s_h, N);

    // packed fp16 weights (pairs along K), one launch per family
    k_packl<<<dim3((192*128 + 255) / 256, L), 256, 0, stream>>>(
        uw1, uw1p, 128, 192 * 128, (size_t)3 * FDIM * FDIM, (size_t)192 * 128);
    k_packl<<<dim3((64*384 + 255) / 256, L), 256, 0, stream>>>(
        uw2, uw2p, 384, 64 * 384, (size_t)FDIM * 3 * FDIM, (size_t)64 * 384);
    k_packl<<<dim3((64*128 + 255) / 256, S), 256, 0, stream>>>(
        ew1, ew1p, 128, 64 * 128, (size_t)FDIM * FDIM, (size_t)64 * 128);

    const int tab_blocks = (TAB_T + 1 + 31) / 32;
    k_table<<<dim3(tab_blocks, L), TH, 0, stream>>>(centers, gamma, fw1, fb1, fw2, fb2, tab, step);
    k_repack4<<<dim3(TAB_T * 128 / 256, L), 256, 0, stream>>>(tab, tab4);

    for (int l = 0; l < L; ++l) {
        const uint4* tab4_l = tab4 + (size_t)l * TAB_T * 128;
        k_gather<<<N, 128, 0, stream>>>(
            rowstart, geo_ci, geo_wd, tab4_l, s_h, v_h,
            m_s_h, vnorm_h, m_v_h, (l > 0) ? 1 : 0, N);
        k_mlp1<<<dim3(NB2, 2), 128, 0, stream>>>(
            s_h, m_s_h, vnorm_h,
            uw1p + (size_t)l * 192 * 128, ub1 + (size_t)l * FDIM, u1_hb, N);
        k_mlp2<<<dim3(NB2, 2), 128, 0, stream>>>(
            u1_hb, uw2p + (size_t)l * 64 * 384, ub2 + (size_t)l * 3 * FDIM,
            s, v_h, m_v_h, s_h, N);
    }

    k_energy3<<<dim3(NB, S), 256, 0, stream>>>(ew1p, eb1, ew2, eb2, s_h, batch, energies, N, S);
    k_vec<<<(N + 3) / 4, 256, 0, stream>>>(v_h, dipole_w, nac_w, batch, dipoles, nac, N);
    k_heads<<<M, 128, 0, stream>>>(aw1, ab1, aw2, ab2, yw1, yb1, yw2, yb2,
                                   energies, nac, lam, phi_y, M, S);
}

// Round 17
// 493.915 us; speedup vs baseline: 1.1153x; 1.1153x over previous
//
#include <hip/hip_runtime.h>
#include <hip/hip_fp16.h>

#define FDIM 128
#define RDIM 20

#define TAB_T 2048              // table cells; TAB_T+1 rows (scalar), TAB_T pair rows
#define TAB_RANGE 12.0f

constexpr int TH = 256;

__device__ __forceinline__ float siluf(float x) { return x / (1.f + __expf(-x)); }

__device__ __forceinline__ void store_h4(__half* p, float a, float b, float c, float d) {
    __half h[4] = {__float2half(a), __float2half(b), __float2half(c), __float2half(d)};
    *(uint2*)p = *(uint2*)h;
}

typedef _Float16 h2v __attribute__((ext_vector_type(2)));
__device__ __forceinline__ float fdot2u(unsigned int a, unsigned int b, float c) {
    union { unsigned int u; h2v h; } ua, ub;
    ua.u = a; ub.u = b;
    return __builtin_amdgcn_fdot2(ua.h, ub.h, c, false);
}

// ---------------------------------------------------------------- init: s = emb[z] (v_h zeroed by memset)
__global__ void k_init(const int* __restrict__ z, const float* __restrict__ emb,
                       float* __restrict__ s, __half* __restrict__ s_h, int N) {
    int i = blockIdx.x * blockDim.x + threadIdx.x;
    if (i >= N * FDIM) return;
    int n = i >> 7, f = i & 127;
    float val = emb[z[n] * FDIM + f];
    s[i] = val;
    s_h[i] = __float2half(val);
}

// ---------------------------------------------------------------- weight pack (strided over blockIdx.y)
__global__ void k_packl(const float* __restrict__ src, unsigned int* __restrict__ dst,
                        int C, int total, size_t sstride, size_t dstride) {
    int l = blockIdx.y;
    const float* sp = src + (size_t)l * sstride;
    unsigned int* dp = dst + (size_t)l * dstride;
    int i = blockIdx.x * 256 + threadIdx.x;
    if (i >= total) return;
    int kp = i / C, c = i - kp * C;
    __half2 h = __halves2half2(__float2half(sp[(2*kp) * C + c]),
                               __float2half(sp[(2*kp+1) * C + c]));
    dp[i] = *(unsigned int*)&h;
}

// ---------------------------------------------------------------- CSR build
__global__ void k_hist(const int* __restrict__ erow, int* __restrict__ cursor, int E) {
    int e = blockIdx.x * blockDim.x + threadIdx.x;
    if (e < E) atomicAdd(&cursor[erow[e]], 1);
}

__global__ __launch_bounds__(256) void k_scan1(const int* __restrict__ cursor,
                                               int* __restrict__ rowstart,
                                               int* __restrict__ bsum, int N) {
    __shared__ int sh[256];
    int tid = threadIdx.x;
    int idx = blockIdx.x * 256 + tid;
    int x = (idx < N) ? cursor[idx] : 0;
    sh[tid] = x;
    __syncthreads();
    #pragma unroll
    for (int off = 1; off < 256; off <<= 1) {
        int t = (tid >= off) ? sh[tid - off] : 0;
        __syncthreads();
        sh[tid] += t;
        __syncthreads();
    }
    if (idx < N) rowstart[idx] = sh[tid] - x;
    if (tid == 255) bsum[blockIdx.x] = sh[255];
}

__global__ __launch_bounds__(256) void k_scan2(int* __restrict__ bsum,
                                               int* __restrict__ rowstart, int nb, int N) {
    __shared__ int sh[256];
    __shared__ int carry;
    int tid = threadIdx.x;
    if (tid == 0) carry = 0;
    __syncthreads();
    for (int base = 0; base < nb; base += 256) {
        int idx = base + tid;
        int x = (idx < nb) ? bsum[idx] : 0;
        sh[tid] = x;
        __syncthreads();
        #pragma unroll
        for (int off = 1; off < 256; off <<= 1) {
            int t = (tid >= off) ? sh[tid - off] : 0;
            __syncthreads();
            sh[tid] += t;
            __syncthreads();
        }
        if (idx < nb) bsum[idx] = carry + sh[tid] - x;
        __syncthreads();
        if (tid == 0) carry += sh[255];
        __syncthreads();
    }
    if (tid == 0) rowstart[N] = carry;
}

__global__ __launch_bounds__(256) void k_scan3(int* __restrict__ rowstart,
                                               int* __restrict__ cursor,
                                               const int* __restrict__ bsum, int N) {
    int idx = blockIdx.x * 256 + threadIdx.x;
    if (idx < N) {
        int val = rowstart[idx] + bsum[blockIdx.x];
        rowstart[idx] = val;
        cursor[idx] = val;
    }
}

// ---------------------------------------------------------------- fill + geometry fused
__global__ void k_fillgeo(const float* __restrict__ pos, const int* __restrict__ erow,
                          const int* __restrict__ ecol, int* __restrict__ cursor,
                          int2* __restrict__ geo_ci, float4* __restrict__ geo_wd,
                          float inv_step, int E) {
    int e = blockIdx.x * blockDim.x + threadIdx.x;
    if (e >= E) return;
    int rw = erow[e], cl = ecol[e];
    int p = atomicAdd(&cursor[rw], 1);
    float dx = pos[cl*3+0] - pos[rw*3+0];
    float dy = pos[cl*3+1] - pos[rw*3+1];
    float dz = pos[cl*3+2] - pos[rw*3+2];
    float dist = sqrtf(dx*dx + dy*dy + dz*dz + 1e-12f);
    float inv = 1.f / (dist + 1e-8f);
    float u = fminf(dist * inv_step, (float)TAB_T);
    int t0 = min((int)u, TAB_T - 1);
    geo_ci[p] = make_int2(cl, t0);
    geo_wd[p] = make_float4(u - (float)t0, dx*inv, dy*inv, dz*inv);
}

// ---------------------------------------------------------------- filter-MLP table build (all layers, fp16 out)
__global__ __launch_bounds__(TH) void k_table(
    const float* __restrict__ centers, const float* __restrict__ gamma,
    const float* __restrict__ fw1b, const float* __restrict__ fb1b,
    const float* __restrict__ fw2b, const float* __restrict__ fb2b,
    __half* __restrict__ tabb, float step)
{
    __shared__ float sh_rbf[32][RDIM];
    __shared__ float sh_ht[FDIM][33];
    __shared__ float sh_w[32][3 * FDIM + 4];

    const int l   = blockIdx.y;
    const float* fw1 = fw1b + (size_t)l * RDIM * FDIM;
    const float* fb1 = fb1b + (size_t)l * FDIM;
    const float* fw2 = fw2b + (size_t)l * FDIM * 3 * FDIM;
    const float* fb2 = fb2b + (size_t)l * 3 * FDIM;
    __half* tab = tabb + (size_t)l * (TAB_T + 1) * 384;

    const int p0  = blockIdx.x * 32;
    const int tid = threadIdx.x;

    for (int i = tid; i < 32 * RDIM; i += TH) {
        int p = i / RDIM, r = i - p * RDIM;
        float d = (float)(p0 + p) * step - centers[r];
        sh_rbf[p][r] = __expf(-gamma[r] * d * d);
    }
    __syncthreads();
    for (int i = tid; i < 32 * FDIM; i += TH) {
        int p = i >> 7, f = i & 127;
        float acc = fb1[f];
        #pragma unroll
        for (int r = 0; r < RDIM; ++r) acc += sh_rbf[p][r] * fw1[r * FDIM + f];
        sh_ht[f][p] = siluf(acc);
    }

    const int eq = tid & 7;
    const int fq = tid >> 3;
    const int f0 = fq * 4;

    float pg[3][4][4];
    #pragma unroll
    for (int g3 = 0; g3 < 3; ++g3)
        #pragma unroll
        for (int ee = 0; ee < 4; ++ee)
            #pragma unroll
            for (int i = 0; i < 4; ++i) pg[g3][ee][i] = fb2[g3 * FDIM + f0 + i];

    const int kkr = tid >> 3;
    const int t8  = tid & 7;
    for (int kc = 0; kc < 4; ++kc) {
        __syncthreads();
        #pragma unroll
        for (int j = 0; j < 12; ++j) {
            int g = (t8 * 12 + j) * 4;
            float4 w4 = *(const float4*)&fw2[(size_t)(kc * 32 + kkr) * (3 * FDIM) + g];
            *(float4*)&sh_w[kkr][g] = w4;
        }
        __syncthreads();
        #pragma unroll 4
        for (int kk = 0; kk < 32; ++kk) {
            float hv[4];
            #pragma unroll
            for (int ee = 0; ee < 4; ++ee) hv[ee] = sh_ht[kc * 32 + kk][4 * eq + ee];
            #pragma unroll
            for (int g3 = 0; g3 < 3; ++g3) {
                float4 w4 = *(const float4*)&sh_w[kk][g3 * FDIM + f0];
                #pragma unroll
                for (int ee = 0; ee < 4; ++ee) {
                    pg[g3][ee][0] += hv[ee] * w4.x;
                    pg[g3][ee][1] += hv[ee] * w4.y;
                    pg[g3][ee][2] += hv[ee] * w4.z;
                    pg[g3][ee][3] += hv[ee] * w4.w;
                }
            }
        }
    }

    #pragma unroll
    for (int ee = 0; ee < 4; ++ee) {
        int pt = p0 + 4 * eq + ee;
        if (pt <= TAB_T) {
            #pragma unroll
            for (int g3 = 0; g3 < 3; ++g3)
                store_h4(&tab[(size_t)pt * 384 + g3 * FDIM + f0],
                         pg[g3][ee][0], pg[g3][ee][1], pg[g3][ee][2], pg[g3][ee][3]);
        }
    }
}

// ---------------------------------------------------------------- repack: tab2[t][j] = {tab[t][j], tab[t+1][j]}
__global__ __launch_bounds__(256) void k_repack(const __half* __restrict__ tab,
                                                __half2* __restrict__ tab2) {
    int l = blockIdx.y;
    const __half* t  = tab  + (size_t)l * (TAB_T + 1) * 384;
    __half2*      t2 = tab2 + (size_t)l * TAB_T * 384;
    int i = blockIdx.x * 256 + threadIdx.x;
    t2[i] = __halves2half2(t[i], t[i + 384]);
}

// ---------------------------------------------------------------- gather message kernel (fp16, tab2 layout)
__global__ __launch_bounds__(128) void k_gather(
    const int* __restrict__ rowstart,
    const int2* __restrict__ geo_ci, const float4* __restrict__ geo_wd,
    const __half2* __restrict__ tab2, const __half* __restrict__ s_h,
    const __half* __restrict__ v_h,
    __half* __restrict__ m_s_h, __half* __restrict__ vnorm_h, __half* __restrict__ m_v_h,
    int withv, int N)
{
    __shared__ int   sh_col[32];
    __shared__ int   sh_t0[32];
    __shared__ float sh_w[32];
    __shared__ float sh_d0[32], sh_d1[32], sh_d2[32];

    const int n   = blockIdx.x;
    const int tid = threadIdx.x;
    const int lo  = rowstart[n], hi = rowstart[n + 1];

    float acc_s = 0.f, av0 = 0.f, av1 = 0.f, av2 = 0.f;

    for (int base = lo; base < hi; base += 32) {
        const int ne = min(32, hi - base);
        __syncthreads();
        if (tid < 32) {
            int idx = base + tid;
            if (tid < ne) {
                int2   ci = geo_ci[idx];
                float4 wd = geo_wd[idx];
                sh_col[tid] = ci.x; sh_t0[tid] = ci.y;
                sh_w[tid] = wd.x;
                sh_d0[tid] = wd.y; sh_d1[tid] = wd.z; sh_d2[tid] = wd.w;
            } else {
                sh_col[tid] = 0; sh_t0[tid] = 0; sh_w[tid] = 0.f;
                sh_d0[tid] = sh_d1[tid] = sh_d2[tid] = 0.f;
            }
        }
        __syncthreads();
        if (withv) {
            #pragma unroll 2
            for (int el = 0; el < ne; ++el) {
                int   cl = sh_col[el];
                int   t0 = sh_t0[el];
                float w  = sh_w[el];
                const __half2* t2 = tab2 + (size_t)t0 * 384 + tid;
                float2 pss2 = __half22float2(t2[0]);
                float2 pvv2 = __half22float2(t2[128]);
                float2 psv2 = __half22float2(t2[256]);
                float pss = pss2.x + w * (pss2.y - pss2.x);
                float pvv = pvv2.x + w * (pvv2.y - pvv2.x);
                float psv = psv2.x + w * (psv2.y - psv2.x);
                float sc = __half2float(s_h[(size_t)cl * FDIM + tid]);
                const __half* vp = v_h + (size_t)cl * 3 * FDIM + tid;
                float svs = psv * sc;
                acc_s += pss * sc;
                av0 += pvv * __half2float(vp[0])        + svs * sh_d0[el];
                av1 += pvv * __half2float(vp[FDIM])     + svs * sh_d1[el];
                av2 += pvv * __half2float(vp[2*FDIM])   + svs * sh_d2[el];
            }
        } else {
            #pragma unroll 2
            for (int el = 0; el < ne; ++el) {
                int   cl = sh_col[el];
                int   t0 = sh_t0[el];
                float w  = sh_w[el];
                const __half2* t2 = tab2 + (size_t)t0 * 384 + tid;
                float2 pss2 = __half22float2(t2[0]);
                float2 psv2 = __half22float2(t2[256]);
                float pss = pss2.x + w * (pss2.y - pss2.x);
                float psv = psv2.x + w * (psv2.y - psv2.x);
                float sc = __half2float(s_h[(size_t)cl * FDIM + tid]);
                float svs = psv * sc;
                acc_s += pss * sc;
                av0 += svs * sh_d0[el];
                av1 += svs * sh_d1[el];
                av2 += svs * sh_d2[el];
            }
        }
    }

    m_s_h[(size_t)n * FDIM + tid]  = __float2half(acc_s);
    vnorm_h[(size_t)n * FDIM + tid] = __float2half(sqrtf(av0*av0 + av1*av1 + av2*av2 + 1e-12f));
    __half* mh = m_v_h + (size_t)n * 3 * FDIM + tid;
    mh[0]      = __float2half(av0);
    mh[FDIM]   = __float2half(av1);
    mh[2*FDIM] = __float2half(av2);
}

// ---------------------------------------------------------------- GEMM 1: u1 = silu(X @ uw1 + ub1), fdot2
__global__ __launch_bounds__(128) void k_mlp1(
    const __half* __restrict__ s_h, const __half* __restrict__ m_s_h,
    const __half* __restrict__ vnorm_h,
    const unsigned int* __restrict__ uw1p,   // [192][128] half2-pairs
    const float* __restrict__ ub1,
    __half* __restrict__ u1_h, int N)
{
    __shared__ unsigned int shA2[8][36];   // [kpair][row]
    __shared__ unsigned int shB2[8][68];   // [kpair][col(64)]

    const int tid = threadIdx.x;           // 0..127
    const int n0  = blockIdx.x * 32;
    const int cb  = blockIdx.y * 64;
    const int tx  = tid & 15, ty = tid >> 4;   // ty 0..7
    const int cA  = tx * 4;
    const int r0  = ty * 4;
    const int rs  = tid >> 2;              // A staging row 0..31
    const int kp0 = (tid & 3) * 2;         // A staging kpair base

    float acc[4][4];
    {
        float4 b4 = *(const float4*)&ub1[cb + cA];
        #pragma unroll
        for (int i = 0; i < 4; ++i) {
            acc[i][0] = b4.x; acc[i][1] = b4.y; acc[i][2] = b4.z; acc[i][3] = b4.w;
        }
    }

    uint2 pa; uint4 pb;

#define MLP1_LOAD(kc) do { \
        pa = make_uint2(0u, 0u); \
        { int kg = (kc) * 16 + (tid & 3) * 4; int n = n0 + rs; \
          if (n < N) { \
              const __half* base; \
              if (kg < 128)      base = &s_h[(size_t)n * FDIM + kg]; \
              else if (kg < 256) base = &m_s_h[(size_t)n * FDIM + kg - 128]; \
              else               base = &vnorm_h[(size_t)n * FDIM + kg - 256]; \
              pa = *(const uint2*)base; } } \
        pb = *(const uint4*)&uw1p[(size_t)((kc)*8 + ty) * FDIM + cb + 4*tx]; \
    } while (0)

    MLP1_LOAD(0);
    for (int kc = 0; kc < 24; ++kc) {
        __syncthreads();
        shA2[kp0][rs]     = pa.x;
        shA2[kp0 + 1][rs] = pa.y;
        *(uint4*)&shB2[ty][4*tx] = pb;
        if (kc + 1 < 24) MLP1_LOAD(kc + 1);
        __syncthreads();
        #pragma unroll
        for (int kp = 0; kp < 8; ++kp) {
            unsigned int b0 = shB2[kp][cA+0], b1 = shB2[kp][cA+1];
            unsigned int b2 = shB2[kp][cA+2], b3 = shB2[kp][cA+3];
            #pragma unroll
            for (int i = 0; i < 4; ++i) {
                unsigned int ai = shA2[kp][r0 + i];
                acc[i][0] = fdot2u(ai, b0, acc[i][0]);
                acc[i][1] = fdot2u(ai, b1, acc[i][1]);
                acc[i][2] = fdot2u(ai, b2, acc[i][2]);
                acc[i][3] = fdot2u(ai, b3, acc[i][3]);
            }
        }
    }
#undef MLP1_LOAD

    #pragma unroll
    for (int i = 0; i < 4; ++i) {
        int n = n0 + r0 + i;
        if (n < N) {
            store_h4(&u1_h[(size_t)n * FDIM + cb + cA],
                     siluf(acc[i][0]), siluf(acc[i][1]), siluf(acc[i][2]), siluf(acc[i][3]));
        }
    }
}

// ---------------------------------------------------------------- GEMM 2: upd = u1 @ uw2 + ub2, fused apply, fdot2
__global__ __launch_bounds__(128) void k_mlp2(
    const __half* __restrict__ u1_h,
    const unsigned int* __restrict__ uw2p,   // [64][384] half2-pairs
    const float* __restrict__ ub2,
    float* __restrict__ s, __half* __restrict__ v_h, const __half* __restrict__ m_v_h,
    __half* __restrict__ s_h, int N)
{
    __shared__ unsigned int shU2[64][33];   // [kpair][row]
    __shared__ unsigned int shB2[8][68];

    const int tid = threadIdx.x;           // 0..127
    const int n0  = blockIdx.x * 32;
    const int cb  = blockIdx.y * 64;
    const int tx  = tid & 15, ty = tid >> 4;
    const int cA  = tx * 4;
    const int r0  = ty * 4;

    #pragma unroll
    for (int it = 0; it < 4; ++it) {
        int idx = it * 128 + tid;
        int row = idx >> 4;          // 0..31
        int c8  = (idx & 15) * 8;
        int n = n0 + row;
        uint4 u = make_uint4(0u,0u,0u,0u);
        if (n < N) u = *(const uint4*)&u1_h[(size_t)n * FDIM + c8];
        int kpb = c8 >> 1;
        shU2[kpb + 0][row] = u.x;
        shU2[kpb + 1][row] = u.y;
        shU2[kpb + 2][row] = u.z;
        shU2[kpb + 3][row] = u.w;
    }

    uint4 pb;
#define MLP2_LOADB(g, kc) do { \
        pb = *(const uint4*)&uw2p[(size_t)((kc)*8 + ty) * (3*FDIM) + (g) * FDIM + cb + 4*tx]; \
    } while (0)

    MLP2_LOADB(0, 0);
    float alpha[4][4];

    for (int g = 0; g < 3; ++g) {
        float acc2[4][4];
        {
            float4 b4 = *(const float4*)&ub2[g * FDIM + cb + cA];
            #pragma unroll
            for (int i = 0; i < 4; ++i) {
                acc2[i][0]=b4.x; acc2[i][1]=b4.y; acc2[i][2]=b4.z; acc2[i][3]=b4.w;
            }
        }
        for (int kc = 0; kc < 8; ++kc) {
            __syncthreads();
            *(uint4*)&shB2[ty][4*tx] = pb;
            if (kc + 1 < 8)      MLP2_LOADB(g, kc + 1);
            else if (g + 1 < 3)  MLP2_LOADB(g + 1, 0);
            __syncthreads();
            #pragma unroll
            for (int kp = 0; kp < 8; ++kp) {
                int kpg = kc * 8 + kp;
                unsigned int b0 = shB2[kp][cA+0], b1 = shB2[kp][cA+1];
                unsigned int b2 = shB2[kp][cA+2], b3 = shB2[kp][cA+3];
                #pragma unroll
                for (int i = 0; i < 4; ++i) {
                    unsigned int uv = shU2[kpg][r0 + i];
                    acc2[i][0] = fdot2u(uv, b0, acc2[i][0]);
                    acc2[i][1] = fdot2u(uv, b1, acc2[i][1]);
                    acc2[i][2] = fdot2u(uv, b2, acc2[i][2]);
                    acc2[i][3] = fdot2u(uv, b3, acc2[i][3]);
                }
            }
        }

        if (g == 0) {
            #pragma unroll
            for (int i = 0; i < 4; ++i) {
                int n = n0 + r0 + i;
                if (n < N) {
                    float4 s0 = *(const float4*)&s[(size_t)n * FDIM + cb + cA];
                    s0.x += acc2[i][0]; s0.y += acc2[i][1]; s0.z += acc2[i][2]; s0.w += acc2[i][3];
                    *(float4*)&s[(size_t)n * FDIM + cb + cA] = s0;
                    store_h4(&s_h[(size_t)n * FDIM + cb + cA], s0.x, s0.y, s0.z, s0.w);
                }
            }
        } else if (g == 1) {
            #pragma unroll
            for (int i = 0; i < 4; ++i)
                #pragma unroll
                for (int j = 0; j < 4; ++j) alpha[i][j] = acc2[i][j];
        } else {
            #pragma unroll
            for (int i = 0; i < 4; ++i) {
                int n = n0 + r0 + i;
                if (n < N) {
                    #pragma unroll
                    for (int k = 0; k < 3; ++k) {
                        __half* vhp = v_h + ((size_t)n * 3 + k) * FDIM + cb + cA;
                        const __half* mp = m_v_h + ((size_t)n * 3 + k) * FDIM + cb + cA;
                        __half vh[4], mh[4];
                        *(uint2*)vh = *(const uint2*)vhp;
                        *(uint2*)mh = *(const uint2*)mp;
                        float nv[4];
                        #pragma unroll
                        for (int j = 0; j < 4; ++j)
                            nv[j] = alpha[i][j] * __half2float(vh[j])
                                  + acc2[i][j] * __half2float(mh[j]);
                        store_h4(vhp, nv[0], nv[1], nv[2], nv[3]);
                    }
                }
            }
        }
    }
#undef MLP2_LOADB
}

// ---------------------------------------------------------------- energy head GEMM, fdot2 (grid = NB x S)
__global__ __launch_bounds__(256) void k_energy3(
    const unsigned int* __restrict__ ew1p,   // [S][64][128] half2-pairs
    const float* __restrict__ eb1,
    const float* __restrict__ ew2, const float* __restrict__ eb2,
    const __half* __restrict__ s_h, const int* __restrict__ batch,
    float* __restrict__ energies, int N, int S)
{
    __shared__ unsigned int shA2[64][66];   // [kpair][row]
    __shared__ unsigned int shB2[8][132];

    const int tid = threadIdx.x;
    const int n0  = blockIdx.x * 64;
    const int st  = blockIdx.y;
    const int tx  = tid & 15, ty = tid >> 4;
    const int cA  = tx * 4, cB = 64 + tx * 4;
    const int r0  = ty * 4;

    #pragma unroll
    for (int it = 0; it < 4; ++it) {
        int idx = it * 256 + tid;
        int row = idx >> 4;
        int c8  = (idx & 15) * 8;
        int n = n0 + row;
        uint4 u = make_uint4(0u,0u,0u,0u);
        if (n < N) u = *(const uint4*)&s_h[(size_t)n * FDIM + c8];
        int kpb = c8 >> 1;
        shA2[kpb + 0][row] = u.x;
        shA2[kpb + 1][row] = u.y;
        shA2[kpb + 2][row] = u.z;
        shA2[kpb + 3][row] = u.w;
    }

    uint2 pb, pb2;
#define EN_LOADB(kc) do { \
        pb = *(const uint2*)&ew1p[(size_t)st * 64 * FDIM + (size_t)((kc)*8 + (tid >> 6)) * FDIM + 2*(tid & 63)]; \
        pb2 = *(const uint2*)&ew1p[(size_t)st * 64 * FDIM + (size_t)((kc)*8 + 4 + (tid >> 6)) * FDIM + 2*(tid & 63)]; \
    } while (0)

    EN_LOADB(0);
    float acc[4][8];
    {
        float4 bA = *(const float4*)&eb1[st * FDIM + cA];
        float4 bB = *(const float4*)&eb1[st * FDIM + cB];
        #pragma unroll
        for (int i = 0; i < 4; ++i) {
            acc[i][0]=bA.x; acc[i][1]=bA.y; acc[i][2]=bA.z; acc[i][3]=bA.w;
            acc[i][4]=bB.x; acc[i][5]=bB.y; acc[i][6]=bB.z; acc[i][7]=bB.w;
        }
    }

    for (int kc = 0; kc < 8; ++kc) {
        __syncthreads();
        {
            int kp = tid >> 6;            // 0..3
            int c2 = 2 * (tid & 63);
            shB2[kp][c2]     = pb.x;  shB2[kp][c2 + 1]     = pb.y;
            shB2[kp + 4][c2] = pb2.x; shB2[kp + 4][c2 + 1] = pb2.y;
        }
        if (kc + 1 < 8) EN_LOADB(kc + 1);
        __syncthreads();
        #pragma unroll
        for (int kp = 0; kp < 8; ++kp) {
            int kpg = kc * 8 + kp;
            unsigned int b0 = shB2[kp][cA+0], b1 = shB2[kp][cA+1];
            unsigned int b2 = shB2[kp][cA+2], b3 = shB2[kp][cA+3];
            unsigned int b4 = shB2[kp][cB+0], b5 = shB2[kp][cB+1];
            unsigned int b6 = shB2[kp][cB+2], b7 = shB2[kp][cB+3];
            #pragma unroll
            for (int i = 0; i < 4; ++i) {
                unsigned int ai = shA2[kpg][r0 + i];
                acc[i][0] = fdot2u(ai, b0, acc[i][0]);
                acc[i][1] = fdot2u(ai, b1, acc[i][1]);
                acc[i][2] = fdot2u(ai, b2, acc[i][2]);
                acc[i][3] = fdot2u(ai, b3, acc[i][3]);
                acc[i][4] = fdot2u(ai, b4, acc[i][4]);
                acc[i][5] = fdot2u(ai, b5, acc[i][5]);
                acc[i][6] = fdot2u(ai, b6, acc[i][6]);
                acc[i][7] = fdot2u(ai, b7, acc[i][7]);
            }
        }
    }
#undef EN_LOADB

    float4 wA = *(const float4*)&ew2[st * FDIM + cA];
    float4 wB = *(const float4*)&ew2[st * FDIM + cB];
    float p[4];
    #pragma unroll
    for (int i = 0; i < 4; ++i) {
        p[i]  = siluf(acc[i][0])*wA.x + siluf(acc[i][1])*wA.y
              + siluf(acc[i][2])*wA.z + siluf(acc[i][3])*wA.w;
        p[i] += siluf(acc[i][4])*wB.x + siluf(acc[i][5])*wB.y
              + siluf(acc[i][6])*wB.z + siluf(acc[i][7])*wB.w;
    }
    #pragma unroll
    for (int m = 1; m <= 8; m <<= 1) {
        #pragma unroll
        for (int i = 0; i < 4; ++i) p[i] += __shfl_xor(p[i], m, 64);
    }
    if (tx == 0) {
        float b2 = eb2[st];
        #pragma unroll
        for (int i = 0; i < 4; ++i) {
            int n = n0 + r0 + i;
            if (n < N) atomicAdd(&energies[batch[n] * S + st], p[i] + b2);
        }
    }
}

// ---------------------------------------------------------------- dipole / nac heads (v_h fp16, half2 lanes)
__global__ void k_vec(const __half* __restrict__ v_h, const float* __restrict__ dipole_w,
                      const float* __restrict__ nac_w, const int* __restrict__ batch,
                      float* __restrict__ dipoles, float* __restrict__ nac, int N)
{
    int n = blockIdx.x * 4 + (threadIdx.x >> 6);
    int lane = threadIdx.x & 63;
    if (n >= N) return;
    int f2 = lane * 2;
    const __half* vb = v_h + (size_t)n * 3 * FDIM;
    float2 v0 = __half22float2(*(const __half2*)&vb[f2]);
    float2 v1 = __half22float2(*(const __half2*)&vb[FDIM + f2]);
    float2 v2 = __half22float2(*(const __half2*)&vb[2*FDIM + f2]);
    float2 wd = *(const float2*)&dipole_w[f2];
    float pd[3];
    pd[0] = wd.x * v0.x + wd.y * v0.y;
    pd[1] = wd.x * v1.x + wd.y * v1.y;
    pd[2] = wd.x * v2.x + wd.y * v2.y;
    float pn[3][3];
    #pragma unroll
    for (int p = 0; p < 3; ++p) {
        float2 wn = *(const float2*)&nac_w[p * FDIM + f2];
        pn[p][0] = wn.x * v0.x + wn.y * v0.y;
        pn[p][1] = wn.x * v1.x + wn.y * v1.y;
        pn[p][2] = wn.x * v2.x + wn.y * v2.y;
    }
    #pragma unroll
    for (int d = 32; d > 0; d >>= 1) {
        #pragma unroll
        for (int k = 0; k < 3; ++k) pd[k] += __shfl_down(pd[k], d, 64);
        #pragma unroll
        for (int p = 0; p < 3; ++p)
            #pragma unroll
            for (int k = 0; k < 3; ++k) pn[p][k] += __shfl_down(pn[p][k], d, 64);
    }
    if (lane == 0) {
        int m = batch[n];
        #pragma unroll
        for (int k = 0; k < 3; ++k) atomicAdd(&dipoles[m * 3 + k], pd[k]);
        #pragma unroll
        for (int p = 0; p < 3; ++p)
            #pragma unroll
            for (int k = 0; k < 3; ++k) atomicAdd(&nac[(m * 3 + p) * 3 + k], pn[p][k]);
    }
}

// ---------------------------------------------------------------- per-molecule heads
__global__ __launch_bounds__(128) void k_heads(
    const float* __restrict__ aw1, const float* __restrict__ ab1,
    const float* __restrict__ aw2, const float* __restrict__ ab2,
    const float* __restrict__ yw1, const float* __restrict__ yb1,
    const float* __restrict__ yw2, const float* __restrict__ yb2,
    const float* __restrict__ energies, const float* __restrict__ nac,
    float* __restrict__ lam, float* __restrict__ phi_y, int M, int S)
{
    __shared__ float sh_in[8];
    __shared__ float sh_red[2];
    int m = blockIdx.x;
    if (m >= M) return;
    int tid = threadIdx.x;
    if (tid == 0) {
        float e0 = energies[m * S];
        for (int j = 0; j < 3; ++j) sh_in[j] = energies[m * S + 1 + j] - e0;
        for (int p = 0; p < 3; ++p) {
            float a = nac[(m * 3 + p) * 3 + 0];
            float b = nac[(m * 3 + p) * 3 + 1];
            float c = nac[(m * 3 + p) * 3 + 2];
            sh_in[3 + p] = sqrtf(a*a + b*b + c*c + 1e-12f);
        }
    }
    __syncthreads();
    float pa = 0.f;
    if (tid < 64) {
        float h = ab1[tid];
        #pragma unroll
        for (int j = 0; j < 3; ++j) h += sh_in[j] * aw1[j * 64 + tid];
        pa = siluf(h) * aw2[tid];
    }
    float h2 = yb1[tid];
    #pragma unroll
    for (int j = 0; j < 6; ++j) h2 += sh_in[j] * yw1[j * 128 + tid];
    float py = siluf(h2) * yw2[tid];
    #pragma unroll
    for (int d = 32; d > 0; d >>= 1) {
        pa += __shfl_down(pa, d, 64);
        py += __shfl_down(py, d, 64);
    }
    int wid = tid >> 6, lane = tid & 63;
    if (lane == 0) sh_red[wid] = py;
    __syncthreads();
    if (tid == 0) {
        lam[m] = pa + ab2[0];
        float yt = sh_red[0] + sh_red[1] + yb2[0];
        phi_y[m] = 1.f / (1.f + __expf(-yt));
    }
}

// ---------------------------------------------------------------- launch
extern "C" void kernel_launch(void* const* d_in, const int* in_sizes, int n_in,
                              void* d_out, int out_size, void* d_ws, size_t ws_size,
                              hipStream_t stream)
{
    const int*   z        = (const int*)  d_in[0];
    const float* pos      = (const float*)d_in[1];
    const int*   eidx     = (const int*)  d_in[2];
    const int*   batch    = (const int*)  d_in[3];
    const float* emb      = (const float*)d_in[5];
    const float* centers  = (const float*)d_in[6];
    const float* gamma    = (const float*)d_in[7];
    const float* fw1      = (const float*)d_in[8];
    const float* fb1      = (const float*)d_in[9];
    const float* fw2      = (const float*)d_in[10];
    const float* fb2      = (const float*)d_in[11];
    const float* uw1      = (const float*)d_in[12];
    const float* ub1      = (const float*)d_in[13];
    const float* uw2      = (const float*)d_in[14];
    const float* ub2      = (const float*)d_in[15];
    const float* ew1      = (const float*)d_in[16];
    const float* eb1      = (const float*)d_in[17];
    const float* ew2      = (const float*)d_in[18];
    const float* eb2      = (const float*)d_in[19];
    const float* dipole_w = (const float*)d_in[20];
    const float* nac_w    = (const float*)d_in[21];
    const float* aw1      = (const float*)d_in[22];
    const float* ab1      = (const float*)d_in[23];
    const float* aw2      = (const float*)d_in[24];
    const float* ab2      = (const float*)d_in[25];
    const float* yw1      = (const float*)d_in[26];
    const float* yb1      = (const float*)d_in[27];
    const float* yw2      = (const float*)d_in[28];
    const float* yb2      = (const float*)d_in[29];

    const int N = in_sizes[0];
    const int E = in_sizes[2] / 2;
    const int S = in_sizes[19];
    const int P = in_sizes[21] / FDIM;
    const int L = in_sizes[9] / FDIM;
    const int M = out_size / (S + 3 + P * 3 + 2);

    const size_t NF = (size_t)N * FDIM;
    float*   s       = (float*)d_ws;                   // NF fp32
    __half*  s_h     = (__half*)(s + NF);              // NF
    __half*  v_h     = s_h + NF;                       // 3 NF (authoritative v)
    __half*  m_s_h   = v_h + 3 * NF;                   // NF
    __half*  vnorm_h = m_s_h + NF;                     // NF
    __half*  m_v_h   = vnorm_h + NF;                   // 3 NF
    __half*  u1_hb   = m_v_h + 3 * NF;                 // NF
    unsigned int* uw1p = (unsigned int*)(u1_hb + NF);  // L * 192*128
    unsigned int* uw2p = uw1p + (size_t)L * 192 * 128; // L * 64*384
    unsigned int* ew1p = uw2p + (size_t)L * 64 * 384;  // S * 64*128
    __half*  tab     = (__half*)(ew1p + (size_t)S * 64 * 128);   // L * (TAB_T+1)*384
    __half2* tab2    = (__half2*)(tab + (size_t)L * (TAB_T + 1) * 384);  // L * TAB_T * 384
    float4*  geo_wd  = (float4*)(tab2 + (size_t)L * TAB_T * 384);        // E
    int2*    geo_ci  = (int2*)(geo_wd + E);                              // E
    int* rowstart = (int*)(geo_ci + E);
    int* cursor   = rowstart + (N + 1);
    int* bsum     = cursor + N;

    float* out      = (float*)d_out;
    float* energies = out;
    float* dipoles  = energies + (size_t)M * S;
    float* nac      = dipoles  + (size_t)M * 3;
    float* lam      = nac      + (size_t)M * P * 3;
    float* phi_y    = lam      + M;

    const int* erow = eidx;
    const int* ecol = eidx + E;

    const float step = TAB_RANGE / (float)TAB_T;
    const float inv_step = (float)TAB_T / TAB_RANGE;
    const int NB  = (N + 63) / 64;
    const int NB2 = (N + 31) / 32;
    const int NSB = (N + 255) / 256;

    hipMemsetAsync(d_out, 0, (size_t)out_size * sizeof(float), stream);
    hipMemsetAsync(cursor, 0, (size_t)N * sizeof(int), stream);
    hipMemsetAsync(v_h, 0, 3 * NF * sizeof(__half), stream);   // fp16 zero == 0x0000
    k_hist<<<(E + 255) / 256, 256, 0, stream>>>(erow, cursor, E);
    k_scan1<<<NSB, 256, 0, stream>>>(cursor, rowstart, bsum, N);
    k_scan2<<<1, 256, 0, stream>>>(bsum, rowstart, NSB, N);
    k_scan3<<<NSB, 256, 0, stream>>>(rowstart, cursor, bsum, N);
    k_fillgeo<<<(E + 255) / 256, 256, 0, stream>>>(pos, erow, ecol, cursor,
                                                   geo_ci, geo_wd, inv_step, E);
    k_init<<<(N * FDIM + 255) / 256, 256, 0, stream>>>(z, emb, s, s_h, N);

    // packed fp16 weights (pairs along K), one launch per family
    k_packl<<<dim3((192*128 + 255) / 256, L), 256, 0, stream>>>(
        uw1, uw1p, 128, 192 * 128, (size_t)3 * FDIM * FDIM, (size_t)192 * 128);
    k_packl<<<dim3((64*384 + 255) / 256, L), 256, 0, stream>>>(
        uw2, uw2p, 384, 64 * 384, (size_t)FDIM * 3 * FDIM, (size_t)64 * 384);
    k_packl<<<dim3((64*128 + 255) / 256, S), 256, 0, stream>>>(
        ew1, ew1p, 128, 64 * 128, (size_t)FDIM * FDIM, (size_t)64 * 128);

    const int tab_blocks = (TAB_T + 1 + 31) / 32;
    k_table<<<dim3(tab_blocks, L), TH, 0, stream>>>(centers, gamma, fw1, fb1, fw2, fb2, tab, step);
    k_repack<<<dim3(TAB_T * 384 / 256, L), 256, 0, stream>>>(tab, tab2);

    for (int l = 0; l < L; ++l) {
        const __half2* tab2_l = tab2 + (size_t)l * TAB_T * 384;
        k_gather<<<N, 128, 0, stream>>>(
            rowstart, geo_ci, geo_wd, tab2_l, s_h, v_h,
            m_s_h, vnorm_h, m_v_h, (l > 0) ? 1 : 0, N);
        k_mlp1<<<dim3(NB2, 2), 128, 0, stream>>>(
            s_h, m_s_h, vnorm_h,
            uw1p + (size_t)l * 192 * 128, ub1 + (size_t)l * FDIM, u1_hb, N);
        k_mlp2<<<dim3(NB2, 2), 128, 0, stream>>>(
            u1_hb, uw2p + (size_t)l * 64 * 384, ub2 + (size_t)l * 3 * FDIM,
            s, v_h, m_v_h, s_h, N);
    }

    k_energy3<<<dim3(NB, S), 256, 0, stream>>>(ew1p, eb1, ew2, eb2, s_h, batch, energies, N, S);
    k_vec<<<(N + 3) / 4, 256, 0, stream>>>(v_h, dipole_w, nac_w, batch, dipoles, nac, N);
    k_heads<<<M, 128, 0, stream>>>(aw1, ab1, aw2, ab2, yw1, yb1, yw2, yb2,
                                   energies, nac, lam, phi_y, M, S);
}